// Round 1
// baseline (171.072 us; speedup 1.0000x reference)
//
#include <hip/hip_runtime.h>

// CTC batch cost, B=256, T=512, C=100 (blank=99), U=32, S=2U+1=65.
// One wave (64 lanes) per batch element. Lane l owns extended state s=l+1.
// State 0 (leading blank) is carried as scalar a00 per lane (no incoming edges:
// alpha_t[0] = alpha_{t-1}[0] + e_blank). DP runs in log2 domain (v_exp_f32 /
// v_log_f32 are base-2); final answer scaled by ln(2).

#define B_ 256
#define T_ 512
#define C_ 100
#define U_ 32
#define BLANK_ 99
#define NEG_ (-1e30f)
#define PF_ 16   // prefetch ring depth (static-indexed -> stays in VGPRs)

__global__ __launch_bounds__(64, 1) void ctc_fwd_kernel(
    const float* __restrict__ y_pred,
    const int*   __restrict__ labels,
    const int*   __restrict__ input_length,
    const int*   __restrict__ label_length,
    float*       __restrict__ out)
{
    const int b    = blockIdx.x;
    const int lane = threadIdx.x;
    const int s    = lane + 1;            // extended state owned by this lane

    const int ilen = min(input_length[b], T_);
    const int llen = label_length[b];

    // per-lane class for emission gather + skip-transition mask
    const int* lab = labels + b * U_;
    const bool isLabel = (s & 1);         // odd states are labels, even are blanks
    int  cls;
    bool canskip;
    if (isLabel) {
        const int k = s >> 1;             // label index
        cls = lab[k];
        const int prev = (k > 0) ? lab[k - 1] : -1;
        canskip = (s >= 3) && (cls != prev);
    } else {
        cls = BLANK_;
        canskip = false;
    }

    // gather pointer for this lane's class; row stride C_ floats
    const float* p = y_pred + ((size_t)b * T_) * C_ + cls;

    // t = 0 init
    float e0  = __builtin_amdgcn_logf(p[0] + 1e-7f);           // log2(y+eps)
    float a0  = (lane == 0) ? e0 : NEG_;                        // alpha[s], s=lane+1
    float a00 = __shfl(e0, 1);                                  // alpha[0] = blank emission @t=0

    // preload prefetch ring for t = 1..PF_
    float ring[PF_];
    #pragma unroll
    for (int j = 0; j < PF_; ++j) ring[j] = p[(size_t)(1 + j) * C_];

    const int nchunks = (ilen + (PF_ - 2)) >> 4;   // covers t = 1 .. ilen-1
    for (int c = 0; c < nchunks; ++c) {
        const int tbase = 1 + (c << 4);
        #pragma unroll
        for (int j = 0; j < PF_; ++j) {
            const int t = tbase + j;
            // emission for this step (loaded PF_ steps ago)
            float e = __builtin_amdgcn_logf(ring[j] + 1e-7f);
            // refill ring for t + PF_ (uniform guard, in-bounds only)
            const int t2 = t + PF_;
            if (t2 < T_) ring[j] = p[(size_t)t2 * C_];

            float eb  = __shfl(e, 1);           // blank emission (lane 1 holds a blank state)
            float up1 = __shfl_up(a0, 1);       // alpha[s-1]
            float up2 = __shfl_up(a0, 2);       // alpha[s-2]
            up1 = (lane == 0) ? a00 : up1;      // lane 0: neighbor is state 0
            up2 = canskip ? up2 : NEG_;         // mask invalid / disallowed skips

            float m   = fmaxf(fmaxf(a0, up1), up2);
            float sum = __builtin_amdgcn_exp2f(a0  - m)
                      + __builtin_amdgcn_exp2f(up1 - m)
                      + __builtin_amdgcn_exp2f(up2 - m);
            float na0 = (m + e) + __builtin_amdgcn_logf(sum);

            const bool upd = (t < ilen);        // freeze past input_length (uniform)
            a0  = upd ? na0        : a0;
            a00 = upd ? (a00 + eb) : a00;
        }
    }

    // readout: ll = logaddexp(alpha[2*llen], alpha[2*llen-1]); out = -ll (in ln units)
    const int last = 2 * llen;                  // >= 32, so both lanes exist
    float aL = __shfl(a0, last - 1);
    float aP = __shfl(a0, last - 2);
    float mm = fmaxf(aL, aP);
    float ll = mm + __builtin_amdgcn_logf(__builtin_amdgcn_exp2f(aL - mm)
                                        + __builtin_amdgcn_exp2f(aP - mm));
    if (lane == 0) out[b] = -0.69314718055994530942f * ll;
}

extern "C" void kernel_launch(void* const* d_in, const int* in_sizes, int n_in,
                              void* d_out, int out_size, void* d_ws, size_t ws_size,
                              hipStream_t stream) {
    const float* y_pred       = (const float*)d_in[0];
    const int*   labels       = (const int*)d_in[1];
    const int*   input_length = (const int*)d_in[2];
    const int*   label_length = (const int*)d_in[3];
    float*       out          = (float*)d_out;

    hipLaunchKernelGGL(ctc_fwd_kernel, dim3(B_), dim3(64), 0, stream,
                       y_pred, labels, input_length, label_length, out);
}

// Round 2
// 170.190 us; speedup vs baseline: 1.0052x; 1.0052x over previous
//
#include <hip/hip_runtime.h>

// CTC batch cost, B=256, T=512, C=100 (blank=99), U=32, S=2U+1=65.
// One wave (64 lanes) per batch element. Lane l owns extended state s=l+1.
// State 0 (leading blank) carried as per-lane scalar a00 (no incoming edges).
// DP in log2 domain; final scaled by ln(2).
// Hot loop is LDS-free: neighbor shifts via DPP wave_shr:1 (pure VALU),
// blank-emission broadcast via v_readlane.

#define B_ 256
#define T_ 512
#define C_ 100
#define U_ 32
#define BLANK_ 99
#define NEG_ (-1e30f)
#define PF_ 32   // prefetch ring depth (static-indexed -> stays in VGPRs)

// lane i <- lane i-1 across the whole wave; lane 0 <- old (bound_ctrl off)
__device__ __forceinline__ float dpp_wave_shr1(float old_, float src) {
    int r = __builtin_amdgcn_update_dpp(__float_as_int(old_), __float_as_int(src),
                                        0x138 /*wave_shr:1*/, 0xF, 0xF, false);
    return __int_as_float(r);
}

__device__ __forceinline__ float bcast_lane(float v, int lane) {
    return __int_as_float(__builtin_amdgcn_readlane(__float_as_int(v), lane));
}

__global__ __launch_bounds__(64, 1) void ctc_fwd_kernel(
    const float* __restrict__ y_pred,
    const int*   __restrict__ labels,
    const int*   __restrict__ input_length,
    const int*   __restrict__ label_length,
    float*       __restrict__ out)
{
    const int b    = blockIdx.x;
    const int lane = threadIdx.x;
    const int s    = lane + 1;            // extended state owned by this lane

    const int ilen = min(input_length[b], T_);
    const int llen = label_length[b];

    // per-lane class for emission gather + skip-transition mask
    const int* lab = labels + b * U_;
    const bool isLabel = (s & 1);         // odd states are labels, even are blanks
    int  cls;
    bool canskip;
    if (isLabel) {
        const int k = s >> 1;             // label index
        cls = lab[k];
        const int prev = (k > 0) ? lab[k - 1] : -1;
        canskip = (s >= 3) && (cls != prev);
    } else {
        cls = BLANK_;
        canskip = false;
    }

    // gather pointer for this lane's class; row stride C_ floats
    const float* p = y_pred + ((size_t)b * T_) * C_ + cls;

    // t = 0 init (log2 domain)
    float e0  = __builtin_amdgcn_logf(p[0] + 1e-7f);
    float a0  = (lane == 0) ? e0 : NEG_;          // alpha[s], s=lane+1
    float a00 = bcast_lane(e0, 1);                // alpha[0] = blank emission @t=0

    // preload prefetch ring for t = 1..PF_
    float ring[PF_];
    #pragma unroll
    for (int j = 0; j < PF_; ++j) ring[j] = p[(size_t)(1 + j) * C_];

    const int nchunks = (ilen + (PF_ - 2)) >> 5;   // ceil((ilen-1)/32)
    for (int c = 0; c < nchunks; ++c) {
        const int tbase = 1 + (c << 5);
        #pragma unroll
        for (int j = 0; j < PF_; ++j) {
            const int t = tbase + j;
            // emission for this step (loaded PF_ steps ago)
            float e = __builtin_amdgcn_logf(ring[j] + 1e-7f);
            // refill ring for t + PF_ (uniform guard, stays in bounds)
            const int t2 = t + PF_;
            if (t2 < T_) ring[j] = p[(size_t)t2 * C_];

            float eb  = bcast_lane(e, 1);            // blank emission (lane 1 is a blank state)
            float up1 = dpp_wave_shr1(a00, a0);      // alpha[s-1]; lane0 gets a00
            float up2 = dpp_wave_shr1(NEG_, up1);    // alpha[s-2]; lanes 0,1 masked below
            up2 = canskip ? up2 : NEG_;

            float m   = fmaxf(fmaxf(a0, up1), up2);
            float sum = __builtin_amdgcn_exp2f(a0  - m)
                      + __builtin_amdgcn_exp2f(up1 - m)
                      + __builtin_amdgcn_exp2f(up2 - m);
            float na0 = (m + e) + __builtin_amdgcn_logf(sum);

            const bool upd = (t < ilen);          // freeze past input_length (uniform)
            a0  = upd ? na0        : a0;
            a00 = upd ? (a00 + eb) : a00;
        }
    }

    // readout: ll = logaddexp(alpha[2*llen], alpha[2*llen-1]); out = -ll (nat units)
    const int last = 2 * llen;                    // >= 32, both lanes exist
    float aL = __shfl(a0, last - 1);
    float aP = __shfl(a0, last - 2);
    float mm = fmaxf(aL, aP);
    float ll = mm + __builtin_amdgcn_logf(__builtin_amdgcn_exp2f(aL - mm)
                                        + __builtin_amdgcn_exp2f(aP - mm));
    if (lane == 0) out[b] = -0.69314718055994530942f * ll;
}

extern "C" void kernel_launch(void* const* d_in, const int* in_sizes, int n_in,
                              void* d_out, int out_size, void* d_ws, size_t ws_size,
                              hipStream_t stream) {
    const float* y_pred       = (const float*)d_in[0];
    const int*   labels       = (const int*)d_in[1];
    const int*   input_length = (const int*)d_in[2];
    const int*   label_length = (const int*)d_in[3];
    float*       out          = (float*)d_out;

    hipLaunchKernelGGL(ctc_fwd_kernel, dim3(B_), dim3(64), 0, stream,
                       y_pred, labels, input_length, label_length, out);
}

// Round 3
// 46.710 us; speedup vs baseline: 3.6624x; 3.6435x over previous
//
#include <hip/hip_runtime.h>

// CTC batch cost, B=256, T=512, C=100 (blank=99), U=32, S=2U+1=65.
// One wave (64 lanes) per batch element. Lane l owns extended state s=l+1.
// State 0 (leading blank) carried as per-lane scalar a00 (no incoming edges).
// DP in log2 domain; final scaled by ln(2).
// Hot loop: LDS-free (DPP lane shifts), and ALL loads unconditional with
// clamped addresses so the 32-deep prefetch ring has a statically countable
// vmcnt pipeline (no per-step vmcnt(0) drain).

#define B_ 256
#define T_ 512
#define C_ 100
#define U_ 32
#define BLANK_ 99
#define NEG_ (-1e30f)
#define PF_ 32   // prefetch ring depth (static-indexed -> stays in VGPRs)

// lane i <- lane i-1 across the whole wave; lane 0 <- old (bound_ctrl off)
__device__ __forceinline__ float dpp_wave_shr1(float old_, float src) {
    int r = __builtin_amdgcn_update_dpp(__float_as_int(old_), __float_as_int(src),
                                        0x138 /*wave_shr:1*/, 0xF, 0xF, false);
    return __int_as_float(r);
}

__device__ __forceinline__ float bcast_lane(float v, int lane) {
    return __int_as_float(__builtin_amdgcn_readlane(__float_as_int(v), lane));
}

__global__ __launch_bounds__(64, 1) void ctc_fwd_kernel(
    const float* __restrict__ y_pred,
    const int*   __restrict__ labels,
    const int*   __restrict__ input_length,
    const int*   __restrict__ label_length,
    float*       __restrict__ out)
{
    const int b    = blockIdx.x;
    const int lane = threadIdx.x;
    const int s    = lane + 1;            // extended state owned by this lane

    const int ilen = min(input_length[b], T_);
    const int llen = label_length[b];

    // per-lane class for emission gather + skip-transition mask
    const int* lab = labels + b * U_;
    const bool isLabel = (s & 1);         // odd states are labels, even are blanks
    int  cls;
    bool canskip;
    if (isLabel) {
        const int k = s >> 1;             // label index
        cls = lab[k];
        const int prev = (k > 0) ? lab[k - 1] : -1;
        canskip = (s >= 3) && (cls != prev);
    } else {
        cls = BLANK_;
        canskip = false;
    }

    // gather pointer for this lane's class; row stride C_ floats
    const float* p = y_pred + ((size_t)b * T_) * C_ + cls;

    // t = 0 init (log2 domain)
    float e0  = __builtin_amdgcn_logf(p[0] + 1e-7f);
    float a0  = (lane == 0) ? e0 : NEG_;          // alpha[s], s=lane+1
    float a00 = bcast_lane(e0, 1);                // alpha[0] = blank emission @t=0

    // preload prefetch ring for t = 1..PF_
    float ring[PF_];
    #pragma unroll
    for (int j = 0; j < PF_; ++j) ring[j] = p[(size_t)(1 + j) * C_];

    // fixed trip count: t = 1..512 in 16 chunks of 32. Steps with t >= ilen
    // are frozen by `upd` (t=512 is always frozen since ilen <= 512).
    #pragma unroll 1
    for (int c = 0; c < 16; ++c) {
        const int tbase = 1 + (c << 5);
        #pragma unroll
        for (int j = 0; j < PF_; ++j) {
            const int t = tbase + j;
            float rv = ring[j];                       // emission prob at step t
            // unconditional refill, clamped address (dead data never consumed)
            const int t2 = min(t + PF_, T_ - 1);
            ring[j] = p[(size_t)t2 * C_];

            float e   = __builtin_amdgcn_logf(rv + 1e-7f);
            float eb  = bcast_lane(e, 1);             // blank emission
            float up1 = dpp_wave_shr1(a00, a0);       // alpha[s-1]; lane0 gets a00
            float up2 = dpp_wave_shr1(NEG_, up1);     // alpha[s-2]
            up2 = canskip ? up2 : NEG_;

            float m   = fmaxf(fmaxf(a0, up1), up2);
            float sum = __builtin_amdgcn_exp2f(a0  - m)
                      + __builtin_amdgcn_exp2f(up1 - m)
                      + __builtin_amdgcn_exp2f(up2 - m);
            float na0 = (m + e) + __builtin_amdgcn_logf(sum);

            const bool upd = (t < ilen);              // freeze past input_length
            a0  = upd ? na0        : a0;
            a00 = upd ? (a00 + eb) : a00;
        }
    }

    // readout: ll = logaddexp(alpha[2*llen], alpha[2*llen-1]); out = -ll (nat units)
    const int last = 2 * llen;                        // >= 32, both lanes exist
    float aL = __shfl(a0, last - 1);
    float aP = __shfl(a0, last - 2);
    float mm = fmaxf(aL, aP);
    float ll = mm + __builtin_amdgcn_logf(__builtin_amdgcn_exp2f(aL - mm)
                                        + __builtin_amdgcn_exp2f(aP - mm));
    if (lane == 0) out[b] = -0.69314718055994530942f * ll;
}

extern "C" void kernel_launch(void* const* d_in, const int* in_sizes, int n_in,
                              void* d_out, int out_size, void* d_ws, size_t ws_size,
                              hipStream_t stream) {
    const float* y_pred       = (const float*)d_in[0];
    const int*   labels       = (const int*)d_in[1];
    const int*   input_length = (const int*)d_in[2];
    const int*   label_length = (const int*)d_in[3];
    float*       out          = (float*)d_out;

    hipLaunchKernelGGL(ctc_fwd_kernel, dim3(B_), dim3(64), 0, stream,
                       y_pred, labels, input_length, label_length, out);
}

// Round 4
// 42.534 us; speedup vs baseline: 4.0220x; 1.0982x over previous
//
#include <hip/hip_runtime.h>

// CTC batch cost, B=256, T=512, C=100 (blank=99), U=32, S=2U+1=65.
// One wave per batch element; lane l owns extended state s=l+1; state 0 is a
// per-lane uniform scalar a00. DP in log2 domain (exact match to reference).
//
// Memory pipeline: inline-asm global_load_dword into two named 32-register
// banks (A/B). Loads for the NEXT chunk are issued before computing the
// current chunk; one counted `s_waitcnt vmcnt(32)` + sched_barrier(0) per
// chunk. Compiler cannot sink these loads (asm volatile order is preserved),
// so steady-state memory stall ~0; cost = serial LSE chain only.

#define B_ 256
#define T_ 512
#define C_ 100
#define U_ 32
#define BLANK_ 99
#define NEG_ (-1e30f)

__device__ __forceinline__ float dpp_wave_shr1(float old_, float src) {
    int r = __builtin_amdgcn_update_dpp(__float_as_int(old_), __float_as_int(src),
                                        0x138 /*wave_shr:1*/, 0xF, 0xF, false);
    return __int_as_float(r);
}

__device__ __forceinline__ float bcast_lane(float v, int lane) {
    return __int_as_float(__builtin_amdgcn_readlane(__float_as_int(v), lane));
}

// Issue 32 per-lane gather loads for t = TB..TB+31 (clamped) into bank RV.
#define ISSUE32(RV, TB)                                                        \
    _Pragma("unroll")                                                          \
    for (int j = 0; j < 32; ++j) {                                             \
        const int tt = min((TB) + j, T_ - 1);                                  \
        const float* ga = p + (size_t)tt * C_;                                 \
        asm volatile("global_load_dword %0, %1, off"                           \
                     : "=v"(RV[j]) : "v"(ga));                                 \
    }

// Wait until at most 32 vector loads outstanding (= the just-issued bank),
// then pin the schedule so no use drifts above the wait.
#define WAIT_BANK()                                                            \
    asm volatile("s_waitcnt vmcnt(32)" ::: "memory");                          \
    __builtin_amdgcn_sched_barrier(0);

// One DP step consuming raw prob RV at time TT.
#define STEP(RV, TT)                                                           \
    {                                                                          \
        const int t = (TT);                                                    \
        float e   = __builtin_amdgcn_logf((RV) + 1e-7f);                       \
        float eb  = bcast_lane(e, 1);                                          \
        float up1 = dpp_wave_shr1(a00, a0);                                    \
        float up2 = dpp_wave_shr1(NEG_, up1);                                  \
        up2 = canskip ? up2 : NEG_;                                            \
        float m   = fmaxf(fmaxf(a0, up1), up2);                                \
        float sum = __builtin_amdgcn_exp2f(a0  - m)                            \
                  + __builtin_amdgcn_exp2f(up1 - m)                            \
                  + __builtin_amdgcn_exp2f(up2 - m);                           \
        float na0 = (m + e) + __builtin_amdgcn_logf(sum);                      \
        const bool upd = (t < ilen);                                           \
        a0  = upd ? na0        : a0;                                           \
        a00 = upd ? (a00 + eb) : a00;                                          \
    }

__global__ __launch_bounds__(64, 1) void ctc_fwd_kernel(
    const float* __restrict__ y_pred,
    const int*   __restrict__ labels,
    const int*   __restrict__ input_length,
    const int*   __restrict__ label_length,
    float*       __restrict__ out)
{
    const int b    = blockIdx.x;
    const int lane = threadIdx.x;
    const int s    = lane + 1;

    const int ilen = min(input_length[b], T_);
    const int llen = label_length[b];

    const int* lab = labels + b * U_;
    const bool isLabel = (s & 1);
    int  cls;
    bool canskip;
    if (isLabel) {
        const int k = s >> 1;
        cls = lab[k];
        const int prev = (k > 0) ? lab[k - 1] : -1;
        canskip = (s >= 3) && (cls != prev);
    } else {
        cls = BLANK_;
        canskip = false;
    }

    const float* p = y_pred + ((size_t)b * T_) * C_ + cls;

    // t = 0 init (log2 domain)
    float e0  = __builtin_amdgcn_logf(p[0] + 1e-7f);
    float a0  = (lane == 0) ? e0 : NEG_;
    float a00 = bcast_lane(e0, 1);

    float rvA[32], rvB[32];

    // prologue: bank A <- chunk 0 (t = 1..32)
    ISSUE32(rvA, 1)

    // 16 chunks of 32 steps (t = 1..512); outer unrolled x2 for static banks.
    #pragma unroll 1
    for (int i = 0; i < 8; ++i) {
        const int tA = 1 + (i * 64);        // chunk 2i   (in bank A)
        const int tB = tA + 32;             // chunk 2i+1 (in bank B)

        ISSUE32(rvB, tB)                    // prefetch next chunk
        WAIT_BANK()                         // bank A resident
        #pragma unroll
        for (int j = 0; j < 32; ++j) STEP(rvA[j], tA + j)

        ISSUE32(rvA, tB + 32)               // prefetch chunk 2i+2 (clamped)
        WAIT_BANK()                         // bank B resident
        #pragma unroll
        for (int j = 0; j < 32; ++j) STEP(rvB[j], tB + j)
    }
    asm volatile("s_waitcnt vmcnt(0)" ::: "memory");  // drain dead prefetch

    // readout: ll = logaddexp(alpha[2*llen], alpha[2*llen-1]); out = -ll (nat)
    const int last = 2 * llen;              // in [32, 64]
    float aL = __shfl(a0, last - 1);
    float aP = __shfl(a0, last - 2);
    float mm = fmaxf(aL, aP);
    float ll = mm + __builtin_amdgcn_logf(__builtin_amdgcn_exp2f(aL - mm)
                                        + __builtin_amdgcn_exp2f(aP - mm));
    if (lane == 0) out[b] = -0.69314718055994530942f * ll;
}

extern "C" void kernel_launch(void* const* d_in, const int* in_sizes, int n_in,
                              void* d_out, int out_size, void* d_ws, size_t ws_size,
                              hipStream_t stream) {
    const float* y_pred       = (const float*)d_in[0];
    const int*   labels       = (const int*)d_in[1];
    const int*   input_length = (const int*)d_in[2];
    const int*   label_length = (const int*)d_in[3];
    float*       out          = (float*)d_out;

    hipLaunchKernelGGL(ctc_fwd_kernel, dim3(B_), dim3(64), 0, stream,
                       y_pred, labels, input_length, label_length, out);
}

// Round 5
// 27.301 us; speedup vs baseline: 6.2660x; 1.5580x over previous
//
#include <hip/hip_runtime.h>

// CTC batch cost, B=256, T=512, C=100 (blank=99), U=32, S=2U+1=65.
// Meet-in-the-middle: per batch, wave 0 runs the forward DP over rows 1..m,
// wave 1 runs the backward (beta) DP over rows ilen-1..m+1 (m=(ilen-1)>>1).
// ll = LSE_j(alpha_m[j] + beta_m[j]) — exact forward/backward identity.
// Each wave's serial chain is halved vs a pure forward pass.
// Forward: lane l owns state l+1, state 0 = scalar a00 (self-loop only).
// Backward: lane l owns state l, state 64 = scalar b64 (self-loop only).
// DPP lane shifts (0x138: lane i<-i-1, empirically verified; 0x130: mirror).
// Inline-asm double-banked loads with counted vmcnt(32) (round-4 pipeline).

#define B_ 256
#define T_ 512
#define C_ 100
#define U_ 32
#define BLANK_ 99
#define NEG_ (-1e30f)

__device__ __forceinline__ float dpp_shr1(float old_, float src) {  // lane i <- i-1; lane0 <- old
    int r = __builtin_amdgcn_update_dpp(__float_as_int(old_), __float_as_int(src),
                                        0x138, 0xF, 0xF, false);
    return __int_as_float(r);
}
__device__ __forceinline__ float dpp_shl1(float old_, float src) {  // lane i <- i+1; lane63 <- old
    int r = __builtin_amdgcn_update_dpp(__float_as_int(old_), __float_as_int(src),
                                        0x130, 0xF, 0xF, false);
    return __int_as_float(r);
}
__device__ __forceinline__ float bcast_lane(float v, int lane) {
    return __int_as_float(__builtin_amdgcn_readlane(__float_as_int(v), lane));
}

// Issue 32 gather loads, rows TB, TB+1, ... (forward) into bank RV.
#define ISSUE_F(RV, TB)                                                        \
    _Pragma("unroll")                                                          \
    for (int j = 0; j < 32; ++j) {                                             \
        const float* ga = p + (size_t)((TB) + j) * C_;                         \
        asm volatile("global_load_dword %0, %1, off" : "=v"(RV[j]) : "v"(ga)); \
    }
// Issue 32 gather loads, rows TB, TB-1, ... (backward) into bank RV.
#define ISSUE_B(RV, TB)                                                        \
    _Pragma("unroll")                                                          \
    for (int j = 0; j < 32; ++j) {                                             \
        const float* ga = p + (size_t)((TB) - j) * C_;                         \
        asm volatile("global_load_dword %0, %1, off" : "=v"(RV[j]) : "v"(ga)); \
    }

#define WAIT_BANK()                                                            \
    asm volatile("s_waitcnt vmcnt(32)" ::: "memory");                          \
    __builtin_amdgcn_sched_barrier(0);

// Forward DP step consuming row T_IDX (raw prob RV); freeze when T_IDX > m.
#define FSTEP(RV, T_IDX)                                                       \
    {                                                                          \
        float e   = __builtin_amdgcn_logf((RV) + 1e-7f);                       \
        float eb  = bcast_lane(e, 1);            /* lane1 = state2 = blank */  \
        float up1 = dpp_shr1(a00, a0);                                         \
        float up2 = dpp_shr1(NEG_, up1);                                       \
        up2 = canskip ? up2 : NEG_;                                            \
        float mx  = fmaxf(fmaxf(a0, up1), up2);                                \
        float sum = __builtin_amdgcn_exp2f(a0  - mx)                           \
                  + __builtin_amdgcn_exp2f(up1 - mx)                           \
                  + __builtin_amdgcn_exp2f(up2 - mx);                          \
        float na  = (mx + e) + __builtin_amdgcn_logf(sum);                     \
        const bool upd = ((T_IDX) <= m);                                       \
        a0  = upd ? na         : a0;                                           \
        a00 = upd ? (a00 + eb) : a00;                                          \
    }

// Backward DP step, step index K (consumes row ilen-1-K); freeze when K >= nb.
#define BSTEP(RV, K)                                                           \
    {                                                                          \
        float e   = __builtin_amdgcn_logf((RV) + 1e-7f);                       \
        float e64 = bcast_lane(e, 0);            /* lane0 = state0 = blank */  \
        float g   = b0 + e;                                                    \
        float g64 = b64 + e64;                                                 \
        float g1  = dpp_shl1(g64, g);            /* lane j <- g[j+1] */        \
        float g2  = dpp_shl1(NEG_, g1);          /* lane j <- g[j+2] */        \
        g2 = csb ? g2 : NEG_;                                                  \
        float mx  = fmaxf(fmaxf(g, g1), g2);                                   \
        float sum = __builtin_amdgcn_exp2f(g  - mx)                            \
                  + __builtin_amdgcn_exp2f(g1 - mx)                            \
                  + __builtin_amdgcn_exp2f(g2 - mx);                           \
        float nbv = mx + __builtin_amdgcn_logf(sum);                           \
        const bool upd = ((K) < nb);                                           \
        b0  = upd ? nbv : b0;                                                  \
        b64 = upd ? g64 : b64;                                                 \
    }

__global__ __launch_bounds__(128, 1) void ctc_fwd_kernel(
    const float* __restrict__ y_pred,
    const int*   __restrict__ labels,
    const int*   __restrict__ input_length,
    const int*   __restrict__ label_length,
    float*       __restrict__ out)
{
    const int b    = blockIdx.x;
    const int lane = threadIdx.x & 63;
    const int wid  = threadIdx.x >> 6;

    const int ilen = min(input_length[b], T_);
    const int llen = label_length[b];
    const int m    = (ilen - 1) >> 1;          // forward computes alpha_m
    const int nb   = ilen - 1 - m;             // backward steps
    const int last = 2 * llen;

    const int* lab = labels + b * U_;

    __shared__ float af[65];
    __shared__ float bf[65];

    float rvA[32], rvB[32];

    if (wid == 0) {
        // ================= forward: alpha over rows 0..m =================
        const int s = lane + 1;
        int  cls;  bool canskip;
        if (s & 1) {
            const int k = s >> 1;
            cls = lab[k];
            const int prev = (k > 0) ? lab[k - 1] : -1;
            canskip = (s >= 3) && (cls != prev);
        } else { cls = BLANK_; canskip = false; }

        const float* p = y_pred + ((size_t)b * T_) * C_ + cls;

        float e0  = __builtin_amdgcn_logf(p[0] + 1e-7f);
        float a0  = (lane == 0) ? e0 : NEG_;
        float a00 = bcast_lane(e0, 1);

        ISSUE_F(rvA, 1)
        #pragma unroll 1
        for (int i = 0; i < 4; ++i) {
            const int tA = 1 + i * 64;
            ISSUE_F(rvB, tA + 32)
            WAIT_BANK()
            #pragma unroll
            for (int j = 0; j < 32; ++j) FSTEP(rvA[j], tA + j)
            ISSUE_F(rvA, tA + 64)
            WAIT_BANK()
            #pragma unroll
            for (int j = 0; j < 32; ++j) FSTEP(rvB[j], tA + 32 + j)
        }
        asm volatile("s_waitcnt vmcnt(0)" ::: "memory");

        af[lane + 1] = a0;
        if (lane == 0) af[0] = a00;
    } else {
        // ================= backward: beta over rows ilen-1..m+1 =================
        const int st = lane;                    // state owned by this lane
        int cls;
        if (st & 1) cls = lab[st >> 1]; else cls = BLANK_;
        // skip edge j -> j+2 allowed iff state j+2 is a label differing from label j
        bool csb = false;
        if ((st & 1) && st <= 61) {
            const int k2 = (st + 2) >> 1;
            csb = (lab[k2] != lab[k2 - 1]);
        }

        const float* p = y_pred + ((size_t)b * T_) * C_ + cls;

        float b0  = (st == last || st == last - 1) ? 0.0f : NEG_;
        float b64 = (last == 64) ? 0.0f : NEG_;

        const int t0 = ilen - 1;
        ISSUE_B(rvA, t0)
        #pragma unroll 1
        for (int i = 0; i < 4; ++i) {
            const int k0 = i * 64;
            ISSUE_B(rvB, t0 - (k0 + 32))
            WAIT_BANK()
            #pragma unroll
            for (int j = 0; j < 32; ++j) BSTEP(rvA[j], k0 + j)
            ISSUE_B(rvA, t0 - (k0 + 64))
            WAIT_BANK()
            #pragma unroll
            for (int j = 0; j < 32; ++j) BSTEP(rvB[j], k0 + 32 + j)
        }
        asm volatile("s_waitcnt vmcnt(0)" ::: "memory");

        bf[lane] = b0;
        if (lane == 0) bf[64] = b64;
    }

    __syncthreads();

    if (wid == 0) {
        // ll = LSE_{j=0..64}(alpha_m[j] + beta_m[j])
        float x   = af[lane] + bf[lane];
        float x64 = af[64] + bf[64];
        float M = x;
        #pragma unroll
        for (int off = 1; off < 64; off <<= 1) M = fmaxf(M, __shfl_xor(M, off));
        M = fmaxf(M, x64);
        float sm = __builtin_amdgcn_exp2f(x - M);
        #pragma unroll
        for (int off = 1; off < 64; off <<= 1) sm += __shfl_xor(sm, off);
        sm += __builtin_amdgcn_exp2f(x64 - M);
        float ll = M + __builtin_amdgcn_logf(sm);
        if (lane == 0) out[b] = -0.69314718055994530942f * ll;
    }
}

extern "C" void kernel_launch(void* const* d_in, const int* in_sizes, int n_in,
                              void* d_out, int out_size, void* d_ws, size_t ws_size,
                              hipStream_t stream) {
    const float* y_pred       = (const float*)d_in[0];
    const int*   labels       = (const int*)d_in[1];
    const int*   input_length = (const int*)d_in[2];
    const int*   label_length = (const int*)d_in[3];
    float*       out          = (float*)d_out;

    hipLaunchKernelGGL(ctc_fwd_kernel, dim3(B_), dim3(128), 0, stream,
                       y_pred, labels, input_length, label_length, out);
}